// Round 1
// baseline (1020.240 us; speedup 1.0000x reference)
//
#include <hip/hip_runtime.h>

namespace {

constexpr int Tn = 512;
constexpr int Sn = 256;
constexpr float EPS = 1e-12f;

__launch_bounds__(256, 1)
__global__ void hmm_kernel(const float* __restrict__ emission,  // [B,T,S]
                           const float* __restrict__ weight,    // [S,S]
                           const float* __restrict__ init,      // [S]
                           float* __restrict__ out)             // [B,T,S]
{
    const int j    = threadIdx.x;   // state / output index, 0..255
    const int b    = blockIdx.x;    // batch row
    const int wave = j >> 6;
    const int lane = j & 63;

    __shared__ __align__(16) float s_m[Sn];        // row max of weight
    __shared__ __align__(16) float s_z[Sn];        // 1 / row sum of exp
    __shared__ __align__(16) float w_buf[2][Sn];   // double-buffered w vector
    __shared__ __align__(16) float partial[2][4];  // wave partial sums

    // ---- prologue 1: per-row max and inv-sum for transition softmax ----
    // thread k scans row k (contiguous per thread; L2-cached, one-time)
    {
        const float* wr = weight + j * Sn;
        float m = -3.402823466e38f;
        #pragma unroll
        for (int i = 0; i < Sn; i += 4) {
            float4 v = *reinterpret_cast<const float4*>(wr + i);
            m = fmaxf(m, fmaxf(fmaxf(v.x, v.y), fmaxf(v.z, v.w)));
        }
        float z0 = 0.f, z1 = 0.f, z2 = 0.f, z3 = 0.f;
        #pragma unroll
        for (int i = 0; i < Sn; i += 4) {
            float4 v = *reinterpret_cast<const float4*>(wr + i);
            z0 += expf(v.x - m);
            z1 += expf(v.y - m);
            z2 += expf(v.z - m);
            z3 += expf(v.w - m);
        }
        s_m[j] = m;
        s_z[j] = 1.f / ((z0 + z1) + (z2 + z3));
    }
    __syncthreads();

    // ---- prologue 2: transition column j -> registers (constant-indexed) ----
    float tc[Sn];
    #pragma unroll
    for (int k = 0; k < Sn; ++k) {
        tc[k] = expf(weight[k * Sn + j] - s_m[k]) * s_z[k];
    }
    __syncthreads();   // everyone done with s_m/s_z before reuse below

    // ---- initial state softmax (same for all rows) ----
    float u;
    {
        float x0 = init[j];
        float m0 = x0;
        #pragma unroll
        for (int o = 32; o >= 1; o >>= 1) m0 = fmaxf(m0, __shfl_xor(m0, o));
        if (lane == 0) s_m[wave] = m0;
        __syncthreads();
        m0 = fmaxf(fmaxf(s_m[0], s_m[1]), fmaxf(s_m[2], s_m[3]));
        float ex = expf(x0 - m0);
        float zz = ex;
        #pragma unroll
        for (int o = 32; o >= 1; o >>= 1) zz += __shfl_xor(zz, o);
        if (lane == 0) s_z[wave] = zz;
        __syncthreads();
        u = ex / (((s_z[0] + s_z[1]) + (s_z[2] + s_z[3])));
    }

    const float* em = emission + ((size_t)b * Tn) * Sn + j;
    float*       op = out      + ((size_t)b * Tn) * Sn + j;

    float e_next = em[0];   // prefetch step 0

    for (int t = 0; t < Tn; ++t) {
        const float e = e_next;
        // prefetch next step's emission (hidden under the FMA loop)
        const int tn = (t + 1 < Tn) ? (t + 1) : t;
        e_next = em[(size_t)tn * Sn];

        // Bayes update (unnormalized); normalization folded into one rcp
        const float w = u * e;

        // wave-level L1 reduce (all values >= 0, abs is identity but cheap)
        float r = fabsf(w);
        #pragma unroll
        for (int o = 32; o >= 1; o >>= 1) r += __shfl_xor(r, o);

        const int p = t & 1;
        w_buf[p][j] = w;
        if (lane == 0) partial[p][wave] = r;
        __syncthreads();

        float4 pp = *reinterpret_cast<const float4*>(partial[p]);
        float l1  = (pp.x + pp.y) + (pp.z + pp.w);
        float inv = 1.f / fmaxf(l1, EPS);

        // next_j = sum_k w_k * P[k][j] ; w broadcast from LDS, P from registers
        const float4* w4 = reinterpret_cast<const float4*>(w_buf[p]);
        float a0 = 0.f, a1 = 0.f, a2 = 0.f, a3 = 0.f;
        float a4 = 0.f, a5 = 0.f, a6 = 0.f, a7 = 0.f;
        #pragma unroll
        for (int q = 0; q < Sn / 8; ++q) {
            float4 v0 = w4[2 * q];
            float4 v1 = w4[2 * q + 1];
            a0 = fmaf(v0.x, tc[8 * q + 0], a0);
            a1 = fmaf(v0.y, tc[8 * q + 1], a1);
            a2 = fmaf(v0.z, tc[8 * q + 2], a2);
            a3 = fmaf(v0.w, tc[8 * q + 3], a3);
            a4 = fmaf(v1.x, tc[8 * q + 4], a4);
            a5 = fmaf(v1.y, tc[8 * q + 5], a5);
            a6 = fmaf(v1.z, tc[8 * q + 6], a6);
            a7 = fmaf(v1.w, tc[8 * q + 7], a7);
        }
        float acc = ((a0 + a1) + (a2 + a3)) + ((a4 + a5) + (a6 + a7));

        // out_t = normalize(acc) ; Σacc == Σw (row-stochastic P) so acc*inv is it
        u = acc * inv;
        op[(size_t)t * Sn] = u;
    }
}

} // namespace

extern "C" void kernel_launch(void* const* d_in, const int* in_sizes, int n_in,
                              void* d_out, int out_size, void* d_ws, size_t ws_size,
                              hipStream_t stream) {
    const float* emission = (const float*)d_in[0];
    const float* weight   = (const float*)d_in[1];
    const float* init     = (const float*)d_in[2];
    float* outp = (float*)d_out;
    const int Bn = in_sizes[0] / (Tn * Sn);   // 128 for the reference shapes

    hipLaunchKernelGGL(hmm_kernel, dim3(Bn), dim3(256), 0, stream,
                       emission, weight, init, outp);
}